// Round 8
// baseline (219.333 us; speedup 1.0000x reference)
//
#include <hip/hip_runtime.h>

typedef __attribute__((ext_vector_type(8)))  short bf16x8;
typedef __attribute__((ext_vector_type(16))) float f32x16;
typedef __attribute__((ext_vector_type(4)))  int   i32x4;

// pack 2 fp32 -> 2 bf16 (RNE)
__device__ __forceinline__ unsigned cvt2(float lo, float hi) {
    unsigned r;
    asm volatile("v_cvt_pk_bf16_f32 %0, %1, %2" : "=v"(r) : "v"(lo), "v"(hi));
    return r;
}
__device__ __forceinline__ bf16x8 pack8(float4 a, float4 b) {
    union { i32x4 i; bf16x8 h; } c;
    c.i.x = cvt2(a.x, a.y);
    c.i.y = cvt2(a.z, a.w);
    c.i.z = cvt2(b.x, b.y);
    c.i.w = cvt2(b.z, b.w);
    return c.h;
}

__device__ __forceinline__ float squash1(float v) {
    float sq = v * v;
    sq += __shfl_xor(sq, 1, 64);
    sq += __shfl_xor(sq, 2, 64);
    sq += __shfl_xor(sq, 4, 64);
    sq += __shfl_xor(sq, 8, 64);
    sq += __shfl_xor(sq, 16, 64);   // reduce over 32-lane c-group
    float scale = sq / (1.0f + sq) / sqrtf(sq + 1e-7f);
    return scale * v;
}

// ws layout (fused path): [counters: 64 int][pad to 4096 B]
//                         [slab: 64 j][16 ic][1024] fp32 = 4 MiB][xf: 2 MiB]
#define SLAB_OFF_F   1024                         // floats (4096 B)
#define XF_OFF_B     (4096 + 4 * 1024 * 1024)     // bytes

// ---------------- xconv: x -> xf fragment order; also zero the j-counters ----
// g = i*64 + l ; lane l holds x[b=l&31][i][d=(l>>5)*8 .. +7] as bf16x8 (16B).
__global__ void caps_xconv(const float* __restrict__ x, uint4* __restrict__ xf,
                           int* __restrict__ counters) {
    int g = blockIdx.x * 256 + threadIdx.x;   // grid 512 -> 131072 threads
    if (g < 64) counters[g] = 0;
    int i = g >> 6, l = g & 63;
    int b = l & 31, h = l >> 5;
    const float4* p = (const float4*)(x + (b * 2048 + i) * 16 + h * 8);
    float4 a = p[0], q = p[1];
    uint4 o;
    o.x = cvt2(a.x, a.y); o.y = cvt2(a.z, a.w);
    o.z = cvt2(q.x, q.y); o.w = cvt2(q.z, q.w);
    xf[g] = o;
}

// ---------------- init (atomic fallback only) ----------------
__global__ void caps_init(float* __restrict__ ws) {
    ws[blockIdx.x * 256 + threadIdx.x] = 0.0f;   // grid 256
}

// ---------------- main: MFMA bf16, depth-2 pipeline, fused finalize ----------
// grid = 64 j * 16 ic (ICHUNK=128) = 1024 blocks, block 256 = 4 waves.
// wave w: i = ibase + w + 4t. One v_mfma_f32_32x32x16_bf16 per step.
// B-frag: lane l reads W[j][i][c=l&31][d=(l>>5)*8..+7] (32B, coalesced)
// A-frag: one coalesced bf16x8 from xf (GATHER=0) or inline fp32 gather (=1).
// FUSED=1: per-j done-counter; the 16th ic-block for j squashes j's slab slice.
template<int FUSED, int GATHER, int ICHUNK>
__global__ __launch_bounds__(256, 4)
void caps_mfma(const float* __restrict__ x, const float* __restrict__ W,
               float* __restrict__ wsbase, const char* __restrict__ xf,
               float* __restrict__ out)
{
    constexpr int NIC = 2048 / ICHUNK;
    constexpr int NT  = ICHUNK / 4;

    const int tid  = threadIdx.x;
    const int w    = tid >> 6;
    const int lane = tid & 63;
    const int m    = lane & 31;   // b for A / c for B
    const int h    = lane >> 5;   // k-half

    const int j     = blockIdx.x / NIC;
    const int ic    = blockIdx.x % NIC;
    const int ibase = ic * ICHUNK;

    int*   counters = (int*)wsbase;
    float* slab     = wsbase + (FUSED ? SLAB_OFF_F : 0);

    const char* Wb = (const char*)W + (((size_t)(j * 2048 + ibase + w)) << 11)
                   + (m << 6) + (h << 5);
    const char* Xb = (const char*)x + ((size_t)m << 17) + ((ibase + w) << 6) + (h << 5);
    const char* Xf = xf + ((ibase + w) << 10) + (lane << 4);

    f32x16 acc = {};

    // depth-2 pipeline, named buffers (rule-#20 safe)
    float4 wA0 = *(const float4*)(Wb);
    float4 wA1 = *(const float4*)(Wb + 16);
    float4 wB0 = *(const float4*)(Wb + 8192);
    float4 wB1 = *(const float4*)(Wb + 8192 + 16);
    bf16x8 xA, xB;
    float4 gA0, gA1, gB0, gB1;
    if (GATHER) {
        gA0 = *(const float4*)(Xb);       gA1 = *(const float4*)(Xb + 16);
        gB0 = *(const float4*)(Xb + 256); gB1 = *(const float4*)(Xb + 256 + 16);
    } else {
        xA = *(const bf16x8*)(Xf);
        xB = *(const bf16x8*)(Xf + 4096);
    }

#pragma unroll 1
    for (int t = 0; t < NT - 2; t += 2) {
        bf16x8 a  = GATHER ? pack8(gA0, gA1) : xA;
        bf16x8 fa = pack8(wA0, wA1);
        wA0 = *(const float4*)(Wb + 16384);
        wA1 = *(const float4*)(Wb + 16384 + 16);
        if (GATHER) {
            gA0 = *(const float4*)(Xb + 512);
            gA1 = *(const float4*)(Xb + 512 + 16);
        } else {
            xA = *(const bf16x8*)(Xf + 8192);
        }
        acc = __builtin_amdgcn_mfma_f32_32x32x16_bf16(a, fa, acc, 0, 0, 0);

        bf16x8 b  = GATHER ? pack8(gB0, gB1) : xB;
        bf16x8 fb = pack8(wB0, wB1);
        wB0 = *(const float4*)(Wb + 24576);
        wB1 = *(const float4*)(Wb + 24576 + 16);
        if (GATHER) {
            gB0 = *(const float4*)(Xb + 768);
            gB1 = *(const float4*)(Xb + 768 + 16);
        } else {
            xB = *(const bf16x8*)(Xf + 12288);
        }
        acc = __builtin_amdgcn_mfma_f32_32x32x16_bf16(b, fb, acc, 0, 0, 0);

        Wb += 16384; Xb += 512; Xf += 8192;
    }
    acc = __builtin_amdgcn_mfma_f32_32x32x16_bf16(
              GATHER ? pack8(gA0, gA1) : xA, pack8(wA0, wA1), acc, 0, 0, 0);
    acc = __builtin_amdgcn_mfma_f32_32x32x16_bf16(
              GATHER ? pack8(gB0, gB1) : xB, pack8(wB0, wB1), acc, 0, 0, 0);

    // ---- cross-wave reduce of C (b = (r&3)+8*(r>>2)+4*(lane>>5), c = lane&31) ----
    __shared__ float red[4096];
#pragma unroll
    for (int r = 0; r < 16; ++r)
        red[w * 1024 + r * 64 + lane] = acc[r];
    __syncthreads();

#pragma unroll
    for (int e = 0; e < 4; ++e) {
        int idx = e * 256 + tid;             // b*32 + c
        int b = idx >> 5, c = idx & 31;
        int l = (((b >> 2) & 1) << 5) + c;
        int r = (b & 3) | (((b >> 3) & 3) << 2);
        float s = red[r * 64 + l] + red[1024 + r * 64 + l]
                + red[2048 + r * 64 + l] + red[3072 + r * 64 + l];
        if (FUSED)
            slab[(j * NIC + ic) * 1024 + idx] = s;     // [j][ic][b*32+c], 4KB contig
        else
            slab[(ic * 32 + b) * 2048 + j * 32 + c] = s;
    }

    if (FUSED) {
        // release: make slab writes visible device-wide, then count this block
        __shared__ int lastflag;
        __threadfence();
        if (tid == 0) {
            int done = atomicAdd(&counters[j], 1);
            lastflag = (done == NIC - 1);
        }
        __syncthreads();
        if (lastflag) {
            __threadfence();   // acquire: see other blocks' slab writes
            const float* sj = slab + j * NIC * 1024;
#pragma unroll
            for (int e = 0; e < 4; ++e) {
                int idx = e * 256 + tid;     // b*32 + c
                float v = 0.0f;
#pragma unroll
                for (int k = 0; k < NIC; ++k) v += sj[k * 1024 + idx];
                v *= (1.0f / 64.0f);
                int b = idx >> 5, c = idx & 31;
                out[b * 2048 + j * 32 + c] = squash1(v);
            }
        }
    }
}

// ---------------- standalone finalize (fallback paths) ----------------
template<int NIC>
__global__ void caps_finalize(const float* __restrict__ ws, float* __restrict__ out) {
    int o = blockIdx.x * 256 + threadIdx.x;   // b*2048 + j*32 + c ; grid 256
    int b = o >> 11;
    int rest = o & 2047;
    float v = 0.0f;
#pragma unroll
    for (int k = 0; k < NIC; ++k) v += ws[(k * 32 + b) * 2048 + rest];
    v *= (1.0f / 64.0f);
    out[o] = squash1(v);
}

__global__ void caps_finalize_a(const float* __restrict__ ws, float* __restrict__ out) {
    int o = blockIdx.x * 256 + threadIdx.x;
    float v = ws[o] * (1.0f / 64.0f);
    out[o] = squash1(v);
}

extern "C" void kernel_launch(void* const* d_in, const int* in_sizes, int n_in,
                              void* d_out, int out_size, void* d_ws, size_t ws_size,
                              hipStream_t stream) {
    (void)in_sizes; (void)n_in; (void)out_size;
    const float* x = (const float*)d_in[0];   // (32, 2048, 16) fp32
    const float* W = (const float*)d_in[1];   // (64, 2048, 32, 16) fp32
    float* out = (float*)d_out;               // (32, 64, 32) fp32
    float* ws  = (float*)d_ws;

    const size_t need_fused = (size_t)XF_OFF_B + (size_t)2048 * 1024;  // ~6.3 MiB

    if (ws_size >= need_fused) {
        char* xf = (char*)d_ws + XF_OFF_B;
        hipLaunchKernelGGL(caps_xconv,                dim3(512),  dim3(256), 0, stream,
                           x, (uint4*)xf, (int*)d_ws);
        hipLaunchKernelGGL((caps_mfma<1, 0, 128>),    dim3(1024), dim3(256), 0, stream,
                           x, W, ws, xf, out);
    } else if (ws_size >= (size_t)16 * 65536 * sizeof(float)) {   // 4 MiB slab
        hipLaunchKernelGGL((caps_mfma<0, 1, 128>),    dim3(1024), dim3(256), 0, stream,
                           x, W, ws, (const char*)0, out);
        hipLaunchKernelGGL((caps_finalize<16>),       dim3(256),  dim3(256), 0, stream,
                           ws, out);
    } else {
        float* acc_buf = (ws_size >= (size_t)65536 * sizeof(float)) ? ws : out;
        hipLaunchKernelGGL(caps_init,                 dim3(256),  dim3(256), 0, stream, acc_buf);
        // atomic fallback: reuse slab=ws path with MODE emulation via finalize_a
        hipLaunchKernelGGL((caps_mfma<0, 1, 128>),    dim3(1024), dim3(256), 0, stream,
                           x, W, acc_buf, (const char*)0, out);
        hipLaunchKernelGGL(caps_finalize_a,           dim3(256),  dim3(256), 0, stream,
                           acc_buf, out);
    }
}

// Round 9
// 52.946 us; speedup vs baseline: 4.1426x; 4.1426x over previous
//
#include <hip/hip_runtime.h>

typedef __attribute__((ext_vector_type(8)))  short bf16x8;
typedef __attribute__((ext_vector_type(16))) float f32x16;
typedef __attribute__((ext_vector_type(4)))  int   i32x4;

// pack 2 fp32 -> 2 bf16 (RNE)
__device__ __forceinline__ unsigned cvt2(float lo, float hi) {
    unsigned r;
    asm volatile("v_cvt_pk_bf16_f32 %0, %1, %2" : "=v"(r) : "v"(lo), "v"(hi));
    return r;
}
__device__ __forceinline__ bf16x8 pack8(float4 a, float4 b) {
    union { i32x4 i; bf16x8 h; } c;
    c.i.x = cvt2(a.x, a.y);
    c.i.y = cvt2(a.z, a.w);
    c.i.z = cvt2(b.x, b.y);
    c.i.w = cvt2(b.z, b.w);
    return c.h;
}

__device__ __forceinline__ float squash1(float v) {
    float sq = v * v;
    sq += __shfl_xor(sq, 1, 64);
    sq += __shfl_xor(sq, 2, 64);
    sq += __shfl_xor(sq, 4, 64);
    sq += __shfl_xor(sq, 8, 64);
    sq += __shfl_xor(sq, 16, 64);   // reduce over 32-lane c-group
    float scale = sq / (1.0f + sq) / sqrtf(sq + 1e-7f);
    return scale * v;
}

// ---------------- xconv: x -> xf fragment order; zero the 256 KiB acc buffer ----
// g = i*64 + l ; lane l holds x[b=l&31][i][d=(l>>5)*8 .. +7] as bf16x8 (16B).
__global__ void caps_xconv(const float* __restrict__ x, uint4* __restrict__ xf,
                           float* __restrict__ accbuf) {
    int g = blockIdx.x * 256 + threadIdx.x;   // grid 512 -> 131072 threads
    if (g < 65536) accbuf[g] = 0.0f;          // re-zeroed EVERY call (deterministic)
    int i = g >> 6, l = g & 63;
    int b = l & 31, h = l >> 5;
    const float4* p = (const float4*)(x + (b * 2048 + i) * 16 + h * 8);
    float4 a = p[0], q = p[1];
    uint4 o;
    o.x = cvt2(a.x, a.y); o.y = cvt2(a.z, a.w);
    o.z = cvt2(q.x, q.y); o.w = cvt2(q.z, q.w);
    xf[g] = o;
}

// ---------------- init (fallback only) ----------------
__global__ void caps_init(float* __restrict__ ws) {
    ws[blockIdx.x * 256 + threadIdx.x] = 0.0f;   // grid 256
}

// ---------------- main: MFMA bf16, distance-4 pipeline (R6 structure) ----------
// grid = 64 j * (2048/ICHUNK) ic ; block 256 = 4 waves; wave w: i = ibase + w + 4t.
// B-frag: lane l reads W[j][i][c=l&31][d=(l>>5)*8..+7] (32B, coalesced 2KB/wave)
// A-frag (GATHER=0): one coalesced bf16x8 from xf. (GATHER=1): inline fp32 gather.
// MODE=0: slab partial writes [ic][b][j*32+c]. MODE=1: atomicAdd into acc[b*2048+j*32+c].
template<int MODE, int GATHER, int ICHUNK>
__global__ __launch_bounds__(256, 4)
void caps_mfma(const float* __restrict__ x, const float* __restrict__ W,
               float* __restrict__ ws, const char* __restrict__ xf)
{
    constexpr int NIC = 2048 / ICHUNK;   // ic count
    constexpr int NT  = ICHUNK / 4;      // steps per wave

    const int tid  = threadIdx.x;
    const int w    = tid >> 6;
    const int lane = tid & 63;
    const int m    = lane & 31;   // b for A / c for B
    const int h    = lane >> 5;   // k-half

    const int j     = blockIdx.x / NIC;
    const int ic    = blockIdx.x % NIC;
    const int ibase = ic * ICHUNK;

    const char* Wb = (const char*)W + (((size_t)(j * 2048 + ibase + w)) << 11)
                   + (m << 6) + (h << 5);
    const char* Xb = (const char*)x + ((size_t)m << 17) + ((ibase + w) << 6) + (h << 5);
    const char* Xf = xf + ((ibase + w) << 10) + (lane << 4);

    f32x16 acc = {};

    float4 wv[4][2];
    bf16x8 xa[4];
    float4 xg[4][2];

#pragma unroll
    for (int s = 0; s < 4; ++s) {
        wv[s][0] = *(const float4*)(Wb + s * 8192);
        wv[s][1] = *(const float4*)(Wb + s * 8192 + 16);
        if (GATHER) {
            xg[s][0] = *(const float4*)(Xb + s * 256);
            xg[s][1] = *(const float4*)(Xb + s * 256 + 16);
        } else {
            xa[s] = *(const bf16x8*)(Xf + s * 4096);
        }
    }

#pragma unroll 1
    for (int t = 0; t < NT - 4; t += 4) {
#pragma unroll
        for (int s = 0; s < 4; ++s) {
            bf16x8 afrag = GATHER ? pack8(xg[s][0], xg[s][1]) : xa[s];
            bf16x8 bfrag = pack8(wv[s][0], wv[s][1]);
            wv[s][0] = *(const float4*)(Wb + (s + 4) * 8192);
            wv[s][1] = *(const float4*)(Wb + (s + 4) * 8192 + 16);
            if (GATHER) {
                xg[s][0] = *(const float4*)(Xb + (s + 4) * 256);
                xg[s][1] = *(const float4*)(Xb + (s + 4) * 256 + 16);
            } else {
                xa[s] = *(const bf16x8*)(Xf + (s + 4) * 4096);
            }
            acc = __builtin_amdgcn_mfma_f32_32x32x16_bf16(afrag, bfrag, acc, 0, 0, 0);
        }
        Wb += 4 * 8192; Xb += 4 * 256; Xf += 4 * 4096;
    }
#pragma unroll
    for (int s = 0; s < 4; ++s) {
        bf16x8 afrag = GATHER ? pack8(xg[s][0], xg[s][1]) : xa[s];
        acc = __builtin_amdgcn_mfma_f32_32x32x16_bf16(
                  afrag, pack8(wv[s][0], wv[s][1]), acc, 0, 0, 0);
    }

    // ---- cross-wave reduce of C (b = (r&3)+8*(r>>2)+4*(lane>>5), c = lane&31) ----
    __shared__ float red[4096];
#pragma unroll
    for (int r = 0; r < 16; ++r)
        red[w * 1024 + r * 64 + lane] = acc[r];
    __syncthreads();

#pragma unroll
    for (int e = 0; e < 4; ++e) {
        int idx = e * 256 + tid;             // b*32 + c
        int b = idx >> 5, c = idx & 31;
        int l = (((b >> 2) & 1) << 5) + c;
        int r = (b & 3) | (((b >> 3) & 3) << 2);
        float s = red[r * 64 + l] + red[1024 + r * 64 + l]
                + red[2048 + r * 64 + l] + red[3072 + r * 64 + l];
        if (MODE == 0)
            ws[(ic * 32 + b) * 2048 + j * 32 + c] = s;   // slab [ic][b][j*32+c]
        else
            atomicAdd(&ws[b * 2048 + j * 32 + c], s);    // 2M adds, 32/address
    }
}

// ---------------- finalize: slab-reduce path (fallback) ----------------
template<int NIC>
__global__ void caps_finalize(const float* __restrict__ ws, float* __restrict__ out) {
    int o = blockIdx.x * 256 + threadIdx.x;   // b*2048 + j*32 + c ; grid 256
    int b = o >> 11;
    int rest = o & 2047;
    float v = 0.0f;
#pragma unroll
    for (int k = 0; k < NIC; ++k) v += ws[(k * 32 + b) * 2048 + rest];
    out[o] = squash1(v * (1.0f / 64.0f));
}

// ---------------- finalize: acc already reduced (primary) ----------------
__global__ void caps_finalize_a(const float* __restrict__ ws, float* __restrict__ out) {
    int o = blockIdx.x * 256 + threadIdx.x;   // grid 256
    out[o] = squash1(ws[o] * (1.0f / 64.0f));
}

extern "C" void kernel_launch(void* const* d_in, const int* in_sizes, int n_in,
                              void* d_out, int out_size, void* d_ws, size_t ws_size,
                              hipStream_t stream) {
    (void)in_sizes; (void)n_in; (void)out_size;
    const float* x = (const float*)d_in[0];   // (32, 2048, 16) fp32
    const float* W = (const float*)d_in[1];   // (64, 2048, 32, 16) fp32
    float* out = (float*)d_out;               // (32, 64, 32) fp32
    float* ws  = (float*)d_ws;

    // primary layout: acc 256 KiB @0, xf 2 MiB @256 KiB
    const size_t ACC_F   = 65536;                       // floats
    const size_t XF_B    = (size_t)2048 * 1024;         // bytes
    const size_t need    = ACC_F * 4 + XF_B;            // 2.25 MiB

    if (ws_size >= need) {
        char* xf = (char*)d_ws + ACC_F * 4;
        hipLaunchKernelGGL(caps_xconv,             dim3(512),  dim3(256), 0, stream,
                           x, (uint4*)xf, ws);
        hipLaunchKernelGGL((caps_mfma<1, 0, 64>),  dim3(2048), dim3(256), 0, stream,
                           x, W, ws, xf);
        hipLaunchKernelGGL(caps_finalize_a,        dim3(256),  dim3(256), 0, stream,
                           ws, out);
    } else if (ws_size >= (size_t)32 * 65536 * sizeof(float)) {   // 8 MiB slab, gather
        hipLaunchKernelGGL((caps_mfma<0, 1, 64>),  dim3(2048), dim3(256), 0, stream,
                           x, W, ws, (const char*)0);
        hipLaunchKernelGGL((caps_finalize<32>),    dim3(256),  dim3(256), 0, stream,
                           ws, out);
    } else {
        float* acc_buf = (ws_size >= ACC_F * sizeof(float)) ? ws : out;
        hipLaunchKernelGGL(caps_init,              dim3(256),  dim3(256), 0, stream, acc_buf);
        hipLaunchKernelGGL((caps_mfma<1, 1, 64>),  dim3(2048), dim3(256), 0, stream,
                           x, W, acc_buf, (const char*)0);
        hipLaunchKernelGGL(caps_finalize_a,        dim3(256),  dim3(256), 0, stream,
                           acc_buf, out);
    }
}